// Round 8
// baseline (296.691 us; speedup 1.0000x reference)
//
#include <hip/hip_runtime.h>
#include <hip/hip_bf16.h>

typedef __attribute__((ext_vector_type(8))) short bf16x8;
typedef __attribute__((ext_vector_type(4))) float f32x4;

// fp32 -> bf16 RNE
__device__ __forceinline__ short f2bf(float f) {
    __hip_bfloat16 h = __float2bfloat16(f);
    return *reinterpret_cast<short*>(&h);
}

// Grid map (256 rows per block, rows_l = 20000*(2l+1); all rows_l % 32 == 0):
// blocks per l: 79,235,391,547,704,860 ; cumulative: 0,79,314,705,1252,1956,2816
__global__ void __launch_bounds__(256) combine_mfma_kernel(
    const float* __restrict__ A0, const float* __restrict__ A1,
    const float* __restrict__ A2, const float* __restrict__ A3,
    const float* __restrict__ A4, const float* __restrict__ A5,
    const float* __restrict__ W, float* __restrict__ out)
{
    int b = (int)blockIdx.x;
    int l, boff;
    if      (b <   79) { l = 0; boff = 0;    }
    else if (b <  314) { l = 1; boff = 79;   }
    else if (b <  705) { l = 2; boff = 314;  }
    else if (b < 1252) { l = 3; boff = 705;  }
    else if (b < 1956) { l = 4; boff = 1252; }
    else               { l = 5; boff = 1956; }
    const float* A = (l==0)?A0:(l==1)?A1:(l==2)?A2:(l==3)?A3:(l==4)?A4:A5;
    const int rows = 20000 * (2*l + 1);
    const int row_start = (b - boff) * 256;
    const int nsteps = min(256, rows - row_start) >> 5;   // 32-row steps
    const size_t outbase = (size_t)20000 * l * l;

    const int tid  = (int)threadIdx.x;
    const int lane = tid & 63;
    const int wv   = tid >> 6;    // wave id 0..3 -> 64-col N-slice
    const int lr   = lane & 15;
    const int lk   = lane >> 4;

    // Double-buffered A step: 2 x (32 rows x 128 fp32) = 2 x 16 KB
    __shared__ float smem[8192];

    // ---- W fragments (used as swapped-MFMA A-operand), registers ----
    const float* Wl = W + (size_t)l * 128 * 256;
    bf16x8 bfrag[4][4];   // [kf][nf]
    #pragma unroll
    for (int kf = 0; kf < 4; ++kf) {
        const int k0 = kf*32 + lk*8;
        #pragma unroll
        for (int nf = 0; nf < 4; ++nf) {
            const int col = wv*64 + nf*16 + lr;
            bf16x8 t;
            #pragma unroll
            for (int j = 0; j < 8; ++j)
                t[j] = f2bf(Wl[(size_t)(k0 + j)*256 + col]);
            bfrag[kf][nf] = t;
        }
    }

    const char* Abase = (const char*)A + (size_t)row_start * 512;  // 512 B/row

    // Stage 32-row step t into LDS buf (linear LDS dest, XOR-pre-swizzled
    // global source; LDS byte L holds global byte L ^ (((L>>9)&7)<<4)).
    auto stage = [&](int t, int buf) {
        const char* tb = Abase + (size_t)t * 16384;
        #pragma unroll
        for (int j = 0; j < 4; ++j) {
            const int lin = wv*4096 + j*1024 + lane*16;       // LDS byte (linear)
            const int src = lin ^ (((lin >> 9) & 7) << 4);    // global byte
            __builtin_amdgcn_global_load_lds(
                (const __attribute__((address_space(1))) void*)(tb + src),
                (__attribute__((address_space(3))) void*)
                    ((char*)smem + buf*16384 + wv*4096 + j*1024),
                16, 0, 0);
        }
    };

    // Fragment read for 16-row sub-tile s: row rr = s*16+lr; rr&7 == lr&7.
    // G0 = rr*512 + kf*128 + lk*32, read at G ^ ((lr&7)<<4): banks 2-way max.
    auto load_frags = [&](int buf, int s, bf16x8* af) {
        const char* base = (const char*)smem + buf*16384 + s*8192;
        const int sw = (lr & 7) << 4;
        #pragma unroll
        for (int kf = 0; kf < 4; ++kf) {
            const int G0 = lr*512 + kf*128 + lk*32;
            f32x4 x = *(const f32x4*)(base + (G0 ^ sw));
            f32x4 y = *(const f32x4*)(base + ((G0 + 16) ^ sw));
            bf16x8 a;
            a[0]=f2bf(x[0]); a[1]=f2bf(x[1]); a[2]=f2bf(x[2]); a[3]=f2bf(x[3]);
            a[4]=f2bf(y[0]); a[5]=f2bf(y[1]); a[6]=f2bf(y[2]); a[7]=f2bf(y[3]);
            af[kf] = a;
        }
    };

    // One 16-row sub-tile: 16 MFMA + 4 nt dwordx4 stores.
    auto do_sub = [&](int t, int buf, int s) {
        bf16x8 af[4];
        load_frags(buf, s, af);
        f32x4 acc[4] = {{0.f,0.f,0.f,0.f},{0.f,0.f,0.f,0.f},
                        {0.f,0.f,0.f,0.f},{0.f,0.f,0.f,0.f}};
        #pragma unroll
        for (int kf = 0; kf < 4; ++kf)
            #pragma unroll
            for (int nf = 0; nf < 4; ++nf)
                acc[nf] = __builtin_amdgcn_mfma_f32_16x16x32_bf16(
                    bfrag[kf][nf], af[kf], acc[nf], 0, 0, 0);
        const int m0 = row_start + t*32 + s*16;
        float* orow = out + (outbase + (size_t)m0 + lr) * 256 + wv*64 + lk*4;
        #pragma unroll
        for (int nf = 0; nf < 4; ++nf)
            __builtin_nontemporal_store(acc[nf], (f32x4*)(orow + nf*16));
    };

    // Prologue: stage step 0, full drain once.
    stage(0, 0);
    asm volatile("s_waitcnt vmcnt(0)" ::: "memory");
    __builtin_amdgcn_s_barrier();

    for (int t = 0; t < nsteps; ++t) {
        const int buf = t & 1;
        if (t + 1 < nsteps) stage(t + 1, buf ^ 1);  // issue early, no wait

        do_sub(t, buf, 0);
        do_sub(t, buf, 1);

        if (t + 1 < nsteps) {
            // Outstanding here: stage(t+1)[4 oldest] + 8 nt stores.
            // vmcnt(8) retires exactly the stage; stores stay in flight.
            asm volatile("s_waitcnt vmcnt(8)" ::: "memory");
            __builtin_amdgcn_s_barrier();
        }
    }
}

extern "C" void kernel_launch(void* const* d_in, const int* in_sizes, int n_in,
                              void* d_out, int out_size, void* d_ws, size_t ws_size,
                              hipStream_t stream) {
    (void)in_sizes; (void)n_in; (void)out_size; (void)d_ws; (void)ws_size;
    combine_mfma_kernel<<<dim3(2816), dim3(256), 0, stream>>>(
        (const float*)d_in[0], (const float*)d_in[1], (const float*)d_in[2],
        (const float*)d_in[3], (const float*)d_in[4], (const float*)d_in[5],
        (const float*)d_in[6], (float*)d_out);
}

// Round 9
// 221.173 us; speedup vs baseline: 1.3414x; 1.3414x over previous
//
#include <hip/hip_runtime.h>
#include <hip/hip_bf16.h>

typedef __attribute__((ext_vector_type(8))) short bf16x8;
typedef __attribute__((ext_vector_type(4))) float f32x4;

// fp32 -> bf16 RNE
__device__ __forceinline__ short f2bf(float f) {
    __hip_bfloat16 h = __float2bfloat16(f);
    return *reinterpret_cast<short*>(&h);
}

// Grid map (256 rows per block, rows_l = 20000*(2l+1); all rows_l % 32 == 0):
// blocks per l: 79,235,391,547,704,860 ; cumulative: 0,79,314,705,1252,1956,2816
__global__ void __launch_bounds__(256) combine_mfma_kernel(
    const float* __restrict__ A0, const float* __restrict__ A1,
    const float* __restrict__ A2, const float* __restrict__ A3,
    const float* __restrict__ A4, const float* __restrict__ A5,
    const float* __restrict__ W, float* __restrict__ out)
{
    int b = (int)blockIdx.x;
    int l, boff;
    if      (b <   79) { l = 0; boff = 0;    }
    else if (b <  314) { l = 1; boff = 79;   }
    else if (b <  705) { l = 2; boff = 314;  }
    else if (b < 1252) { l = 3; boff = 705;  }
    else if (b < 1956) { l = 4; boff = 1252; }
    else               { l = 5; boff = 1956; }
    const float* A = (l==0)?A0:(l==1)?A1:(l==2)?A2:(l==3)?A3:(l==4)?A4:A5;
    const int rows = 20000 * (2*l + 1);
    const int row_start = (b - boff) * 256;
    const int nsteps = min(256, rows - row_start) >> 5;   // 32-row steps
    const size_t outbase = (size_t)20000 * l * l;

    const int tid  = (int)threadIdx.x;
    const int lane = tid & 63;
    const int wv   = tid >> 6;    // wave id 0..3 -> 64-col N-slice
    const int lr   = lane & 15;
    const int lk   = lane >> 4;

    // Double-buffered A step: 2 x (32 rows x 128 fp32) = 2 x 16 KB
    __shared__ float smem[8192];

    // ---- W fragments (used as swapped-MFMA A-operand), registers ----
    const float* Wl = W + (size_t)l * 128 * 256;
    bf16x8 bfrag[4][4];   // [kf][nf]
    #pragma unroll
    for (int kf = 0; kf < 4; ++kf) {
        const int k0 = kf*32 + lk*8;
        #pragma unroll
        for (int nf = 0; nf < 4; ++nf) {
            const int col = wv*64 + nf*16 + lr;
            bf16x8 t;
            #pragma unroll
            for (int j = 0; j < 8; ++j)
                t[j] = f2bf(Wl[(size_t)(k0 + j)*256 + col]);
            bfrag[kf][nf] = t;
        }
    }

    const char* Abase = (const char*)A + (size_t)row_start * 512;  // 512 B/row

    // Stage 32-row step t into LDS buf (linear LDS dest, XOR-pre-swizzled
    // global source; LDS byte L holds global byte L ^ (((L>>9)&7)<<4)).
    auto stage = [&](int t, int buf) {
        const char* tb = Abase + (size_t)t * 16384;
        #pragma unroll
        for (int j = 0; j < 4; ++j) {
            const int lin = wv*4096 + j*1024 + lane*16;       // LDS byte (linear)
            const int src = lin ^ (((lin >> 9) & 7) << 4);    // global byte
            __builtin_amdgcn_global_load_lds(
                (const __attribute__((address_space(1))) void*)(tb + src),
                (__attribute__((address_space(3))) void*)
                    ((char*)smem + buf*16384 + wv*4096 + j*1024),
                16, 0, 0);
        }
    };

    // Fragment read for 16-row sub-tile s: row rr = s*16+lr; rr&7 == lr&7.
    // G0 = rr*512 + kf*128 + lk*32, read at G ^ ((lr&7)<<4): banks 2-way max.
    auto load_frags = [&](int buf, int s, bf16x8* af) {
        const char* base = (const char*)smem + buf*16384 + s*8192;
        const int sw = (lr & 7) << 4;
        #pragma unroll
        for (int kf = 0; kf < 4; ++kf) {
            const int G0 = lr*512 + kf*128 + lk*32;
            f32x4 x = *(const f32x4*)(base + (G0 ^ sw));
            f32x4 y = *(const f32x4*)(base + ((G0 + 16) ^ sw));
            bf16x8 a;
            a[0]=f2bf(x[0]); a[1]=f2bf(x[1]); a[2]=f2bf(x[2]); a[3]=f2bf(x[3]);
            a[4]=f2bf(y[0]); a[5]=f2bf(y[1]); a[6]=f2bf(y[2]); a[7]=f2bf(y[3]);
            af[kf] = a;
        }
    };

    // One 16-row sub-tile: 16 MFMA + 4 plain dwordx4 stores.
    auto do_sub = [&](int t, int buf, int s) {
        bf16x8 af[4];
        load_frags(buf, s, af);
        f32x4 acc[4] = {{0.f,0.f,0.f,0.f},{0.f,0.f,0.f,0.f},
                        {0.f,0.f,0.f,0.f},{0.f,0.f,0.f,0.f}};
        #pragma unroll
        for (int kf = 0; kf < 4; ++kf)
            #pragma unroll
            for (int nf = 0; nf < 4; ++nf)
                acc[nf] = __builtin_amdgcn_mfma_f32_16x16x32_bf16(
                    bfrag[kf][nf], af[kf], acc[nf], 0, 0, 0);
        const int m0 = row_start + t*32 + s*16;
        float* orow = out + (outbase + (size_t)m0 + lr) * 256 + wv*64 + lk*4;
        #pragma unroll
        for (int nf = 0; nf < 4; ++nf)
            *(f32x4*)(orow + nf*16) = acc[nf];
    };

    // Prologue: stage step 0, full drain once.
    stage(0, 0);
    asm volatile("s_waitcnt vmcnt(0)" ::: "memory");
    __builtin_amdgcn_s_barrier();

    for (int t = 0; t < nsteps; ++t) {
        const int buf = t & 1;
        if (t + 1 < nsteps) stage(t + 1, buf ^ 1);  // issue early, no wait

        do_sub(t, buf, 0);
        do_sub(t, buf, 1);

        if (t + 1 < nsteps) {
            // Outstanding here: stage(t+1)[4 oldest] + 8 stores.
            // vmcnt(8) retires exactly the stage; stores stay in flight.
            asm volatile("s_waitcnt vmcnt(8)" ::: "memory");
            __builtin_amdgcn_s_barrier();
        }
    }
}

extern "C" void kernel_launch(void* const* d_in, const int* in_sizes, int n_in,
                              void* d_out, int out_size, void* d_ws, size_t ws_size,
                              hipStream_t stream) {
    (void)in_sizes; (void)n_in; (void)out_size; (void)d_ws; (void)ws_size;
    combine_mfma_kernel<<<dim3(2816), dim3(256), 0, stream>>>(
        (const float*)d_in[0], (const float*)d_in[1], (const float*)d_in[2],
        (const float*)d_in[3], (const float*)d_in[4], (const float*)d_in[5],
        (const float*)d_in[6], (float*)d_out);
}

// Round 10
// 219.692 us; speedup vs baseline: 1.3505x; 1.0067x over previous
//
#include <hip/hip_runtime.h>
#include <hip/hip_bf16.h>

typedef __attribute__((ext_vector_type(8))) short bf16x8;
typedef __attribute__((ext_vector_type(4))) float f32x4;

// fp32 -> bf16 RNE
__device__ __forceinline__ short f2bf(float f) {
    __hip_bfloat16 h = __float2bfloat16(f);
    return *reinterpret_cast<short*>(&h);
}

// Grid map (256 rows per block, rows_l = 20000*(2l+1); all rows_l % 32 == 0):
// blocks per l: 79,235,391,547,704,860 ; cumulative: 0,79,314,705,1252,1956,2816
__global__ void __launch_bounds__(256) combine_mfma_kernel(
    const float* __restrict__ A0, const float* __restrict__ A1,
    const float* __restrict__ A2, const float* __restrict__ A3,
    const float* __restrict__ A4, const float* __restrict__ A5,
    const float* __restrict__ W, float* __restrict__ out)
{
    int b = (int)blockIdx.x;
    int l, boff;
    if      (b <   79) { l = 0; boff = 0;    }
    else if (b <  314) { l = 1; boff = 79;   }
    else if (b <  705) { l = 2; boff = 314;  }
    else if (b < 1252) { l = 3; boff = 705;  }
    else if (b < 1956) { l = 4; boff = 1252; }
    else               { l = 5; boff = 1956; }
    const float* A = (l==0)?A0:(l==1)?A1:(l==2)?A2:(l==3)?A3:(l==4)?A4:A5;
    const int rows = 20000 * (2*l + 1);
    const int row_start = (b - boff) * 256;
    const int nsteps = min(256, rows - row_start) >> 5;   // 32-row steps
    const size_t outbase = (size_t)20000 * l * l;

    const int tid  = (int)threadIdx.x;
    const int lane = tid & 63;
    const int wv   = tid >> 6;    // wave id 0..3 -> 64-col N-slice
    const int lr   = lane & 15;
    const int lk   = lane >> 4;

    // TRIPLE-buffered A step: 3 x (32 rows x 128 fp32) = 3 x 16 KB
    __shared__ float smem[12288];

    // ---- W fragments (used as swapped-MFMA A-operand), registers ----
    const float* Wl = W + (size_t)l * 128 * 256;
    bf16x8 bfrag[4][4];   // [kf][nf]
    #pragma unroll
    for (int kf = 0; kf < 4; ++kf) {
        const int k0 = kf*32 + lk*8;
        #pragma unroll
        for (int nf = 0; nf < 4; ++nf) {
            const int col = wv*64 + nf*16 + lr;
            bf16x8 t;
            #pragma unroll
            for (int j = 0; j < 8; ++j)
                t[j] = f2bf(Wl[(size_t)(k0 + j)*256 + col]);
            bfrag[kf][nf] = t;
        }
    }

    const char* Abase = (const char*)A + (size_t)row_start * 512;  // 512 B/row

    // Stage 32-row step t into LDS buf (linear LDS dest, XOR-pre-swizzled
    // global source; LDS byte L holds global byte L ^ (((L>>9)&7)<<4)).
    auto stage = [&](int t, int buf) {
        const char* tb = Abase + (size_t)t * 16384;
        #pragma unroll
        for (int j = 0; j < 4; ++j) {
            const int lin = wv*4096 + j*1024 + lane*16;       // LDS byte (linear)
            const int src = lin ^ (((lin >> 9) & 7) << 4);    // global byte
            __builtin_amdgcn_global_load_lds(
                (const __attribute__((address_space(1))) void*)(tb + src),
                (__attribute__((address_space(3))) void*)
                    ((char*)smem + buf*16384 + wv*4096 + j*1024),
                16, 0, 0);
        }
    };

    // Fragment read for 16-row sub-tile s: row rr = s*16+lr; rr&7 == lr&7.
    // G0 = rr*512 + kf*128 + lk*32, read at G ^ ((lr&7)<<4): banks 2-way max.
    auto load_frags = [&](int buf, int s, bf16x8* af) {
        const char* base = (const char*)smem + buf*16384 + s*8192;
        const int sw = (lr & 7) << 4;
        #pragma unroll
        for (int kf = 0; kf < 4; ++kf) {
            const int G0 = lr*512 + kf*128 + lk*32;
            f32x4 x = *(const f32x4*)(base + (G0 ^ sw));
            f32x4 y = *(const f32x4*)(base + ((G0 + 16) ^ sw));
            bf16x8 a;
            a[0]=f2bf(x[0]); a[1]=f2bf(x[1]); a[2]=f2bf(x[2]); a[3]=f2bf(x[3]);
            a[4]=f2bf(y[0]); a[5]=f2bf(y[1]); a[6]=f2bf(y[2]); a[7]=f2bf(y[3]);
            af[kf] = a;
        }
    };

    // One 16-row sub-tile: 16 MFMA + 4 plain dwordx4 stores.
    auto do_sub = [&](int t, int buf, int s) {
        bf16x8 af[4];
        load_frags(buf, s, af);
        f32x4 acc[4] = {{0.f,0.f,0.f,0.f},{0.f,0.f,0.f,0.f},
                        {0.f,0.f,0.f,0.f},{0.f,0.f,0.f,0.f}};
        #pragma unroll
        for (int kf = 0; kf < 4; ++kf)
            #pragma unroll
            for (int nf = 0; nf < 4; ++nf)
                acc[nf] = __builtin_amdgcn_mfma_f32_16x16x32_bf16(
                    bfrag[kf][nf], af[kf], acc[nf], 0, 0, 0);
        const int m0 = row_start + t*32 + s*16;
        float* orow = out + (outbase + (size_t)m0 + lr) * 256 + wv*64 + lk*4;
        #pragma unroll
        for (int nf = 0; nf < 4; ++nf)
            *(f32x4*)(orow + nf*16) = acc[nf];
    };

    // Prologue: stage steps 0 and 1; wait only for step 0 (oldest 4).
    stage(0, 0);
    if (nsteps > 1) {
        stage(1, 1);
        asm volatile("s_waitcnt vmcnt(4)" ::: "memory");
    } else {
        asm volatile("s_waitcnt vmcnt(0)" ::: "memory");
    }
    __builtin_amdgcn_s_barrier();

    int cbuf = 0;
    for (int t = 0; t < nsteps; ++t) {
        // Issue stage(t+2) into the buffer being vacated this iteration+1.
        if (t + 2 < nsteps) {
            int sbuf = cbuf + 2; if (sbuf >= 3) sbuf -= 3;
            stage(t + 2, sbuf);
        }

        do_sub(t, cbuf, 0);
        do_sub(t, cbuf, 1);

        if (t + 1 < nsteps) {
            // In-order vmcnt: newest 12 = stage(t+2)[4] + this iter's stores[8].
            // vmcnt(12) retires all older ops, incl. stage(t+1) -> buf ready.
            // Tail (no stage(t+2) issued): newest 8 = stores -> vmcnt(8).
            if (t + 2 < nsteps) {
                asm volatile("s_waitcnt vmcnt(12)" ::: "memory");
            } else {
                asm volatile("s_waitcnt vmcnt(8)" ::: "memory");
            }
            __builtin_amdgcn_s_barrier();
        }
        ++cbuf; if (cbuf >= 3) cbuf = 0;
    }
}

extern "C" void kernel_launch(void* const* d_in, const int* in_sizes, int n_in,
                              void* d_out, int out_size, void* d_ws, size_t ws_size,
                              hipStream_t stream) {
    (void)in_sizes; (void)n_in; (void)out_size; (void)d_ws; (void)ws_size;
    combine_mfma_kernel<<<dim3(2816), dim3(256), 0, stream>>>(
        (const float*)d_in[0], (const float*)d_in[1], (const float*)d_in[2],
        (const float*)d_in[3], (const float*)d_in[4], (const float*)d_in[5],
        (const float*)d_in[6], (float*)d_out);
}